// Round 4
// baseline (181.053 us; speedup 1.0000x reference)
//
#include <hip/hip_runtime.h>
#include <hip/hip_bf16.h>

// Shapes (fixed by the problem)
#define NB   16    // batch
#define NC   512   // channels
#define NSPA 1024  // h*w
#define NO3  1536  // 3*C
#define GN_EPS 1e-5f
#define SCL 0.044194173824159216f  // 512^-0.5

typedef __bf16 bf16x8 __attribute__((ext_vector_type(8)));
typedef __bf16 bf16x4 __attribute__((ext_vector_type(4)));
typedef float  f32x4  __attribute__((ext_vector_type(4)));

typedef __attribute__((address_space(3))) void lds_t;
typedef const __attribute__((address_space(1))) void gl_t;
#define GLDS16(g, l) __builtin_amdgcn_global_load_lds((gl_t*)(g), (lds_t*)(l), 16, 0, 0)

__device__ __forceinline__ __bf16 tob(float f) { return (__bf16)f; }

// ---------------------------------------------------------------------------
// K1: GroupNorm stats -> per (b,c) affine coefs: xn = x*coefA + coefB
// ---------------------------------------------------------------------------
__global__ void gn_stats_kernel(const float* __restrict__ x,
                                const float* __restrict__ gn_scale,
                                const float* __restrict__ gn_bias,
                                float* __restrict__ coefA,
                                float* __restrict__ coefB) {
  const int bg = blockIdx.x;
  const int b = bg >> 5, g = bg & 31;
  const float4* base = (const float4*)(x + (size_t)(b * NC + g * 16) * NSPA);
  const int tid = threadIdx.x;
  float s = 0.f, ss = 0.f;
#pragma unroll
  for (int i = 0; i < 16; ++i) {
    float4 v = base[i * 256 + tid];
    s  += (v.x + v.y) + (v.z + v.w);
    ss += (v.x * v.x + v.y * v.y) + (v.z * v.z + v.w * v.w);
  }
#pragma unroll
  for (int off = 32; off; off >>= 1) {
    s  += __shfl_xor(s, off);
    ss += __shfl_xor(ss, off);
  }
  __shared__ float rs[4], rss[4];
  const int wave = tid >> 6, lane = tid & 63;
  if (lane == 0) { rs[wave] = s; rss[wave] = ss; }
  __syncthreads();
  if (tid < 16) {
    float S  = rs[0] + rs[1] + rs[2] + rs[3];
    float SS = rss[0] + rss[1] + rss[2] + rss[3];
    float mean = S * (1.f / 16384.f);
    float var  = SS * (1.f / 16384.f) - mean * mean;
    float rstd = rsqrtf(var + GN_EPS);
    int c = g * 16 + tid;
    float a = gn_scale[c] * rstd;
    coefA[b * NC + c] = a;
    coefB[b * NC + c] = gn_bias[c] - mean * a;
  }
}

// ---------------------------------------------------------------------------
// K2a: pack weights fp32 -> bf16, natural [o][c]
// ---------------------------------------------------------------------------
__global__ void pack_w_kernel(const float* __restrict__ wq, const float* __restrict__ wo,
                              __bf16* __restrict__ wqb, __bf16* __restrict__ wob) {
  const int t = blockIdx.x * 256 + threadIdx.x;
  const int NQ = NO3 * NC / 4;
  float4 v;
  __bf16* dst;
  if (t < NQ) { v = ((const float4*)wq)[t]; dst = wqb + (size_t)t * 4; }
  else        { v = ((const float4*)wo)[t - NQ]; dst = wob + (size_t)(t - NQ) * 4; }
  bf16x4 w;
  w[0] = tob(v.x); w[1] = tob(v.y); w[2] = tob(v.z); w[3] = tob(v.w);
  *(bf16x4*)dst = w;
}

// ---------------------------------------------------------------------------
// K2b: xnT[b][n][c] = bf16(GN(x))  (64c x 64n LDS transpose tiles)
// ---------------------------------------------------------------------------
__global__ void pack_x_kernel(const float* __restrict__ x,
                              const float* __restrict__ coefA,
                              const float* __restrict__ coefB,
                              __bf16* __restrict__ xnT) {
  const int n0 = blockIdx.x * 64, c0 = blockIdx.y * 64, b = blockIdx.z;
  __shared__ __bf16 l[64][72];  // [n][c]
  const int tid = threadIdx.x;
  const int cl = tid >> 2, seg = (tid & 3) * 16;
  const float ca = coefA[b * NC + c0 + cl], cb = coefB[b * NC + c0 + cl];
  const float4* src = (const float4*)(x + (size_t)(b * NC + c0 + cl) * NSPA + n0 + seg);
#pragma unroll
  for (int i = 0; i < 4; ++i) {
    float4 v = src[i];
    l[seg + i * 4 + 0][cl] = tob(v.x * ca + cb);
    l[seg + i * 4 + 1][cl] = tob(v.y * ca + cb);
    l[seg + i * 4 + 2][cl] = tob(v.z * ca + cb);
    l[seg + i * 4 + 3][cl] = tob(v.w * ca + cb);
  }
  __syncthreads();
#pragma unroll
  for (int i = 0; i < 2; ++i) {
    const int chunk = tid + i * 256;
    const int row = chunk >> 3, s = chunk & 7;
    *(bf16x8*)(xnT + (size_t)(b * NSPA + n0 + row) * NC + c0 + s * 8) =
        *(const bf16x8*)&l[row][s * 8];
  }
}

// ---------------------------------------------------------------------------
// GEMM core v4: BK=32, 3-slot LDS ring, counted vmcnt (never 0 in steady
// state), raw s_barrier (NOT __syncthreads — that would drain vmcnt(0)).
// 512 threads = 8 waves (2 M x 4 N). Per-wave output 16*M_REP x 64
// (M_REP x 4 frags of 16x16, one MFMA-K=32 per BK step).
//
// LDS tiles pair-packed: logical [rows][32] stored as phys [rows/2][64]
// (two logical rows per 128B physical row) so the XOR swizzle spreads over
// 8 16B-slots: phys slot pc holds logical chunk pc^(prow&7); reads use the
// same involution -> 2 lanes per 16B span per 16-lane group = conflict-free
// (same scheme class that measured 0 conflicts in r3).
//
// Ring schedule, iteration t (slot st = t%3):
//   1. issue stage(t+2) -> slot (t+2)%3   [safe: that slot last read at
//      t-1, and the barrier ending t-1 was passed by all waves]
//   2. ds_read frags from st, MFMA (setprio-wrapped)
//   3. s_waitcnt vmcnt(L)  [L = loads of stage(t+2); certifies stage(t+1)
//      landed, ~2 compute phases after issue]; s_barrier
// ---------------------------------------------------------------------------
template <int M_REP>  // 8 -> BM=256, 4 -> BM=128
__device__ __forceinline__ void stage32(const __bf16* __restrict__ A, int lda,
                                        const __bf16* __restrict__ B, int ldb,
                                        int k0, __bf16* sAs, __bf16* sBs) {
  const int tid = threadIdx.x;
  // B tile: 256 logical rows x 32 -> phys [128][64] = 1024 16B chunks
#pragma unroll
  for (int l = 0; l < 2; ++l) {
    const int idx = tid + l * 512;
    const int prow = idx >> 3;
    const int pcs = (idx & 7) ^ (prow & 7);          // inverse-swizzled source
    const int row = prow * 2 + (pcs >> 2);
    GLDS16(B + (size_t)row * ldb + k0 + (pcs & 3) * 8, sBs + idx * 8);
  }
  // A tile: 32*M_REP logical rows -> M_REP*128 chunks
#pragma unroll
  for (int l = 0; l < M_REP / 4; ++l) {
    const int idx = tid + l * 512;
    const int prow = idx >> 3;
    const int pcs = (idx & 7) ^ (prow & 7);
    const int row = prow * 2 + (pcs >> 2);
    GLDS16(A + (size_t)row * lda + k0 + (pcs & 3) * 8, sAs + idx * 8);
  }
}

#define WAIT_CNT(MR)                                                       \
  if constexpr (MR == 8) asm volatile("s_waitcnt vmcnt(4)" ::: "memory"); \
  else                   asm volatile("s_waitcnt vmcnt(3)" ::: "memory");

template <int M_REP>
__device__ __forceinline__ void gemm_core32(const __bf16* __restrict__ A, int lda,
                                            const __bf16* __restrict__ B, int ldb,
                                            int K, __bf16* sA, __bf16* sB,
                                            f32x4 (*acc)[4]) {
  const int tid = threadIdx.x;
  const int lane = tid & 63, wave = tid >> 6;
  const int wmB = (wave >> 2) * 16 * M_REP;
  const int wn = (wave & 3) * 64;
  const int fr = lane & 15, fgh = lane >> 4;  // k-chunk 0..3
  const int AS = M_REP * 1024;                // A slot elems
  const int BS = 8192;                        // B slot elems
  const int nt = K >> 5;

  stage32<M_REP>(A, lda, B, ldb, 0,  sA,      sB);
  stage32<M_REP>(A, lda, B, ldb, 32, sA + AS, sB + BS);
  WAIT_CNT(M_REP);                 // stage(0) landed
  __builtin_amdgcn_s_barrier();

  int slot = 0;
  for (int t = 0; t < nt; ++t) {
    if (t + 2 < nt) {
      const int s2 = (slot + 2 >= 3) ? slot - 1 : slot + 2;
      stage32<M_REP>(A, lda, B, ldb, (t + 2) * 32, sA + s2 * AS, sB + s2 * BS);
    }
    const __bf16* cA = sA + slot * AS;
    const __bf16* cB = sB + slot * BS;
    bf16x8 af[M_REP], bfr[4];
#pragma unroll
    for (int mi = 0; mi < M_REP; ++mi) {
      const int row = wmB + mi * 16 + fr;
      const int prow = row >> 1;
      const int sc = (((row & 1) << 2) | fgh) ^ (prow & 7);
      af[mi] = *(const bf16x8*)(cA + prow * 64 + sc * 8);
    }
#pragma unroll
    for (int ni = 0; ni < 4; ++ni) {
      const int row = wn + ni * 16 + fr;
      const int prow = row >> 1;
      const int sc = (((row & 1) << 2) | fgh) ^ (prow & 7);
      bfr[ni] = *(const bf16x8*)(cB + prow * 64 + sc * 8);
    }
    __builtin_amdgcn_s_setprio(1);
#pragma unroll
    for (int mi = 0; mi < M_REP; ++mi)
#pragma unroll
      for (int ni = 0; ni < 4; ++ni)
        acc[mi][ni] = __builtin_amdgcn_mfma_f32_16x16x32_bf16(af[mi], bfr[ni], acc[mi][ni], 0, 0, 0);
    __builtin_amdgcn_s_setprio(0);
    if (t + 1 < nt) {
      WAIT_CNT(M_REP);             // stage(t+1) landed (issued last iter)
      __builtin_amdgcn_s_barrier();
    }
    slot = (slot + 1 >= 3) ? 0 : slot + 1;
  }
}

// ---------------------------------------------------------------------------
// K3: QKV GEMM (BM=256). C[o][n] = Wqkv[o][c] x xnT[n][c]^T (+bias).
//   o <  1024 (q,k): transposed store -> qk[b][n][o]
//   o >= 1024 (v)  : natural store    -> v[b][o-1024][n]
// grid (4, 6, NB) x 512 thr
// ---------------------------------------------------------------------------
__global__ __launch_bounds__(512, 2) void qkv_gemm_kernel(
    const __bf16* __restrict__ wqb, const __bf16* __restrict__ xnT,
    const float* __restrict__ bqkv, __bf16* __restrict__ qk, __bf16* __restrict__ v) {
  const int n0 = blockIdx.x * 256, m0 = blockIdx.y * 256, b = blockIdx.z;
  __shared__ __align__(16) __bf16 sA[3 * 8 * 1024];  // 48 KB
  __shared__ __align__(16) __bf16 sB[3 * 8192];      // 48 KB
  f32x4 acc[8][4] = {};
  gemm_core32<8>(wqb + (size_t)m0 * NC, NC, xnT + ((size_t)b * NSPA + n0) * NC, NC,
                 NC, sA, sB, acc);

  const int lane = threadIdx.x & 63, wave = threadIdx.x >> 6;
  const int wmB = (wave >> 2) * 128, wn = (wave & 3) * 64;
  const int fr = lane & 15, fq4 = (lane >> 4) * 4;
  if (m0 < NSPA) {
#pragma unroll
    for (int mi = 0; mi < 8; ++mi) {
      const int m = m0 + wmB + mi * 16 + fq4;
      const float4 bias = *(const float4*)(bqkv + m);
#pragma unroll
      for (int ni = 0; ni < 4; ++ni) {
        const int n = n0 + wn + ni * 16 + fr;
        bf16x4 w;
        w[0] = tob(acc[mi][ni][0] + bias.x);
        w[1] = tob(acc[mi][ni][1] + bias.y);
        w[2] = tob(acc[mi][ni][2] + bias.z);
        w[3] = tob(acc[mi][ni][3] + bias.w);
        *(bf16x4*)(qk + ((size_t)b * NSPA + n) * NSPA + m) = w;
      }
    }
  } else {
#pragma unroll
    for (int mi = 0; mi < 8; ++mi) {
      const int m = m0 + wmB + mi * 16 + fq4;
      const float4 bias = *(const float4*)(bqkv + m);
      const int vr = m - NSPA;
#pragma unroll
      for (int ni = 0; ni < 4; ++ni) {
        const int n = n0 + wn + ni * 16 + fr;
        v[((size_t)b * NC + vr + 0) * NSPA + n] = tob(acc[mi][ni][0] + bias.x);
        v[((size_t)b * NC + vr + 1) * NSPA + n] = tob(acc[mi][ni][1] + bias.y);
        v[((size_t)b * NC + vr + 2) * NSPA + n] = tob(acc[mi][ni][2] + bias.z);
        v[((size_t)b * NC + vr + 3) * NSPA + n] = tob(acc[mi][ni][3] + bias.w);
      }
    }
  }
}

// ---------------------------------------------------------------------------
// K4: scores (swapped, BM=256). C[j][i] = k[j][d].q[i][d]; store P[b][i][j]*SCL.
// grid (4, 4, NB) x 512 thr
// ---------------------------------------------------------------------------
__global__ __launch_bounds__(512, 2) void scores_kernel(const __bf16* __restrict__ qk,
                                                        __bf16* __restrict__ P) {
  const int i0 = blockIdx.x * 256, j0 = blockIdx.y * 256, b = blockIdx.z;
  const __bf16* base = qk + (size_t)b * NSPA * NSPA;
  __shared__ __align__(16) __bf16 sA[3 * 8 * 1024];
  __shared__ __align__(16) __bf16 sB[3 * 8192];
  f32x4 acc[8][4] = {};
  gemm_core32<8>(base + (size_t)j0 * NSPA + NC, NSPA, base + (size_t)i0 * NSPA, NSPA,
                 NC, sA, sB, acc);

  const int lane = threadIdx.x & 63, wave = threadIdx.x >> 6;
  const int wmB = (wave >> 2) * 128, wn = (wave & 3) * 64;
  const int fr = lane & 15, fq4 = (lane >> 4) * 4;
#pragma unroll
  for (int mi = 0; mi < 8; ++mi) {
    const int j = j0 + wmB + mi * 16 + fq4;
#pragma unroll
    for (int ni = 0; ni < 4; ++ni) {
      const int i = i0 + wn + ni * 16 + fr;
      bf16x4 w;
      w[0] = tob(acc[mi][ni][0] * SCL);
      w[1] = tob(acc[mi][ni][1] * SCL);
      w[2] = tob(acc[mi][ni][2] * SCL);
      w[3] = tob(acc[mi][ni][3] * SCL);
      *(bf16x4*)(P + ((size_t)b * NSPA + i) * NSPA + j) = w;
    }
  }
}

// ---------------------------------------------------------------------------
// K5: in-place row softmax on bf16 P
// ---------------------------------------------------------------------------
__global__ void softmax_kernel(__bf16* __restrict__ P) {
  const int row = blockIdx.x;
  __bf16* p = P + (size_t)row * NSPA;
  const int tid = threadIdx.x;
  bf16x4 v = *((const bf16x4*)p + tid);
  float f0 = (float)v[0], f1 = (float)v[1], f2 = (float)v[2], f3 = (float)v[3];
  float m = fmaxf(fmaxf(f0, f1), fmaxf(f2, f3));
#pragma unroll
  for (int off = 32; off; off >>= 1) m = fmaxf(m, __shfl_xor(m, off));
  __shared__ float red[4];
  const int wave = tid >> 6, lane = tid & 63;
  if (lane == 0) red[wave] = m;
  __syncthreads();
  m = fmaxf(fmaxf(red[0], red[1]), fmaxf(red[2], red[3]));
  float e0 = __expf(f0 - m), e1 = __expf(f1 - m), e2 = __expf(f2 - m), e3 = __expf(f3 - m);
  float s = (e0 + e1) + (e2 + e3);
#pragma unroll
  for (int off = 32; off; off >>= 1) s += __shfl_xor(s, off);
  __syncthreads();
  if (lane == 0) red[wave] = s;
  __syncthreads();
  s = (red[0] + red[1]) + (red[2] + red[3]);
  const float inv = 1.f / s;
  v[0] = tob(e0 * inv); v[1] = tob(e1 * inv); v[2] = tob(e2 * inv); v[3] = tob(e3 * inv);
  *((bf16x4*)p + tid) = v;
}

// ---------------------------------------------------------------------------
// K6: PV (BM=128). C[d][i] = v[d][j].P[i][j]; transposed store -> attn[b][i][d].
// grid (4, 4, NB) x 512 thr, K=1024
// ---------------------------------------------------------------------------
__global__ __launch_bounds__(512, 2) void pv_kernel(const __bf16* __restrict__ v,
                                                    const __bf16* __restrict__ P,
                                                    __bf16* __restrict__ attn) {
  const int i0 = blockIdx.x * 256, d0 = blockIdx.y * 128, b = blockIdx.z;
  __shared__ __align__(16) __bf16 sA[3 * 4 * 1024];  // 24 KB
  __shared__ __align__(16) __bf16 sB[3 * 8192];      // 48 KB
  f32x4 acc[4][4] = {};
  gemm_core32<4>(v + ((size_t)b * NC + d0) * NSPA, NSPA,
                 P + ((size_t)b * NSPA + i0) * NSPA, NSPA, NSPA, sA, sB, acc);

  const int lane = threadIdx.x & 63, wave = threadIdx.x >> 6;
  const int wmB = (wave >> 2) * 64, wn = (wave & 3) * 64;
  const int fr = lane & 15, fq4 = (lane >> 4) * 4;
#pragma unroll
  for (int mi = 0; mi < 4; ++mi) {
    const int d = d0 + wmB + mi * 16 + fq4;
#pragma unroll
    for (int ni = 0; ni < 4; ++ni) {
      const int i = i0 + wn + ni * 16 + fr;
      bf16x4 w;
      w[0] = tob(acc[mi][ni][0]);
      w[1] = tob(acc[mi][ni][1]);
      w[2] = tob(acc[mi][ni][2]);
      w[3] = tob(acc[mi][ni][3]);
      *(bf16x4*)(attn + ((size_t)b * NSPA + i) * NC + d) = w;
    }
  }
}

// ---------------------------------------------------------------------------
// K7: out-proj (BM=128). C[o][n] = Wout[o][c].attn[n][c] + bias + x, fp32.
// grid (4, 4, NB) x 512 thr
// ---------------------------------------------------------------------------
__global__ __launch_bounds__(512, 2) void out_gemm_kernel(
    const __bf16* __restrict__ wob, const __bf16* __restrict__ attn,
    const float* __restrict__ bout, const float* __restrict__ x,
    float* __restrict__ out) {
  const int n0 = blockIdx.x * 256, m0 = blockIdx.y * 128, b = blockIdx.z;
  __shared__ __align__(16) __bf16 sA[3 * 4 * 1024];
  __shared__ __align__(16) __bf16 sB[3 * 8192];
  f32x4 acc[4][4] = {};
  gemm_core32<4>(wob + (size_t)m0 * NC, NC, attn + ((size_t)b * NSPA + n0) * NC, NC,
                 NC, sA, sB, acc);

  const int lane = threadIdx.x & 63, wave = threadIdx.x >> 6;
  const int wmB = (wave >> 2) * 64, wn = (wave & 3) * 64;
  const int fr = lane & 15, fq4 = (lane >> 4) * 4;
#pragma unroll
  for (int mi = 0; mi < 4; ++mi) {
    const int m = m0 + wmB + mi * 16 + fq4;
    const float4 bias = *(const float4*)(bout + m);
#pragma unroll
    for (int ni = 0; ni < 4; ++ni) {
      const int n = n0 + wn + ni * 16 + fr;
      const size_t i0x = ((size_t)b * NC + m) * NSPA + n;
      out[i0x + 0 * NSPA] = acc[mi][ni][0] + bias.x + x[i0x + 0 * NSPA];
      out[i0x + 1 * NSPA] = acc[mi][ni][1] + bias.y + x[i0x + 1 * NSPA];
      out[i0x + 2 * NSPA] = acc[mi][ni][2] + bias.z + x[i0x + 2 * NSPA];
      out[i0x + 3 * NSPA] = acc[mi][ni][3] + bias.w + x[i0x + 3 * NSPA];
    }
  }
}

// ---------------------------------------------------------------------------
// Workspace (~66 MB):
//   coefA/coefB: 2x32 KB | xnT/attn: 16 MB | wqb 1.5 MB | wob 0.5 MB
//   v: 16 MB | P: 32 MB.  qk (32 MB) lives in d_out (dead until out_gemm).
// ---------------------------------------------------------------------------
extern "C" void kernel_launch(void* const* d_in, const int* in_sizes, int n_in,
                              void* d_out, int out_size, void* d_ws, size_t ws_size,
                              hipStream_t stream) {
  const float* x        = (const float*)d_in[0];
  const float* gn_scale = (const float*)d_in[3];
  const float* gn_bias  = (const float*)d_in[4];
  const float* w_qkv    = (const float*)d_in[5];
  const float* b_qkv    = (const float*)d_in[6];
  const float* w_out    = (const float*)d_in[7];
  const float* b_out    = (const float*)d_in[8];
  float* out = (float*)d_out;

  char* ws = (char*)d_ws;
  float*  coefA = (float*)ws;                                   // 32 KB
  float*  coefB = coefA + NB * NC;                              // 32 KB
  __bf16* xnT   = (__bf16*)(ws + (64 << 10));                   // 16 MB (also attn)
  __bf16* attn  = xnT;
  __bf16* wqb   = xnT + (size_t)NB * NSPA * NC;                 // 1.5 MB
  __bf16* wob   = wqb + (size_t)NO3 * NC;                       // 0.5 MB
  __bf16* vbuf  = wob + (size_t)NC * NC;                        // 16 MB
  __bf16* P     = vbuf + (size_t)NB * NC * NSPA;                // 32 MB
  __bf16* qk    = (__bf16*)d_out;                               // 32 MB scratch in out

  gn_stats_kernel<<<dim3(NB * 32), 256, 0, stream>>>(x, gn_scale, gn_bias, coefA, coefB);
  pack_w_kernel<<<dim3((NO3 * NC + NC * NC) / 4 / 256), 256, 0, stream>>>(w_qkv, w_out, wqb, wob);
  pack_x_kernel<<<dim3(NSPA / 64, NC / 64, NB), 256, 0, stream>>>(x, coefA, coefB, xnT);
  qkv_gemm_kernel<<<dim3(4, 6, NB), 512, 0, stream>>>(wqb, xnT, b_qkv, qk, vbuf);
  scores_kernel<<<dim3(4, 4, NB), 512, 0, stream>>>(qk, P);
  softmax_kernel<<<dim3(NB * NSPA), 256, 0, stream>>>(P);
  pv_kernel<<<dim3(4, 4, NB), 512, 0, stream>>>(vbuf, P, attn);
  out_gemm_kernel<<<dim3(4, 4, NB), 512, 0, stream>>>(wob, attn, b_out, x, out);
}

// Round 5
// 155.072 us; speedup vs baseline: 1.1675x; 1.1675x over previous
//
#include <hip/hip_runtime.h>
#include <hip/hip_bf16.h>

// Shapes (fixed by the problem)
#define NB   16    // batch
#define NC   512   // channels
#define NSPA 1024  // h*w
#define NO3  1536  // 3*C
#define GN_EPS 1e-5f
#define SCL 0.044194173824159216f  // 512^-0.5

typedef __bf16 bf16x8 __attribute__((ext_vector_type(8)));
typedef __bf16 bf16x4 __attribute__((ext_vector_type(4)));
typedef float  f32x4  __attribute__((ext_vector_type(4)));

typedef __attribute__((address_space(3))) void lds_t;
typedef const __attribute__((address_space(1))) void gl_t;
#define GLDS16(g, l) __builtin_amdgcn_global_load_lds((gl_t*)(g), (lds_t*)(l), 16, 0, 0)

__device__ __forceinline__ __bf16 tob(float f) { return (__bf16)f; }

// ---------------------------------------------------------------------------
// K1: GroupNorm stats -> per (b,c) affine coefs: xn = x*coefA + coefB
// ---------------------------------------------------------------------------
__global__ void gn_stats_kernel(const float* __restrict__ x,
                                const float* __restrict__ gn_scale,
                                const float* __restrict__ gn_bias,
                                float* __restrict__ coefA,
                                float* __restrict__ coefB) {
  const int bg = blockIdx.x;
  const int b = bg >> 5, g = bg & 31;
  const float4* base = (const float4*)(x + (size_t)(b * NC + g * 16) * NSPA);
  const int tid = threadIdx.x;
  float s = 0.f, ss = 0.f;
#pragma unroll
  for (int i = 0; i < 16; ++i) {
    float4 v = base[i * 256 + tid];
    s  += (v.x + v.y) + (v.z + v.w);
    ss += (v.x * v.x + v.y * v.y) + (v.z * v.z + v.w * v.w);
  }
#pragma unroll
  for (int off = 32; off; off >>= 1) {
    s  += __shfl_xor(s, off);
    ss += __shfl_xor(ss, off);
  }
  __shared__ float rs[4], rss[4];
  const int wave = tid >> 6, lane = tid & 63;
  if (lane == 0) { rs[wave] = s; rss[wave] = ss; }
  __syncthreads();
  if (tid < 16) {
    float S  = rs[0] + rs[1] + rs[2] + rs[3];
    float SS = rss[0] + rss[1] + rss[2] + rss[3];
    float mean = S * (1.f / 16384.f);
    float var  = SS * (1.f / 16384.f) - mean * mean;
    float rstd = rsqrtf(var + GN_EPS);
    int c = g * 16 + tid;
    float a = gn_scale[c] * rstd;
    coefA[b * NC + c] = a;
    coefB[b * NC + c] = gn_bias[c] - mean * a;
  }
}

// ---------------------------------------------------------------------------
// K2a: pack weights fp32 -> bf16, natural [o][c]
// ---------------------------------------------------------------------------
__global__ void pack_w_kernel(const float* __restrict__ wq, const float* __restrict__ wo,
                              __bf16* __restrict__ wqb, __bf16* __restrict__ wob) {
  const int t = blockIdx.x * 256 + threadIdx.x;
  const int NQ = NO3 * NC / 4;
  float4 v;
  __bf16* dst;
  if (t < NQ) { v = ((const float4*)wq)[t]; dst = wqb + (size_t)t * 4; }
  else        { v = ((const float4*)wo)[t - NQ]; dst = wob + (size_t)(t - NQ) * 4; }
  bf16x4 w;
  w[0] = tob(v.x); w[1] = tob(v.y); w[2] = tob(v.z); w[3] = tob(v.w);
  *(bf16x4*)dst = w;
}

// ---------------------------------------------------------------------------
// K2b: xnT[b][n][c] = bf16(GN(x))  (64c x 64n LDS transpose tiles)
// ---------------------------------------------------------------------------
__global__ void pack_x_kernel(const float* __restrict__ x,
                              const float* __restrict__ coefA,
                              const float* __restrict__ coefB,
                              __bf16* __restrict__ xnT) {
  const int n0 = blockIdx.x * 64, c0 = blockIdx.y * 64, b = blockIdx.z;
  __shared__ __bf16 l[64][72];  // [n][c]
  const int tid = threadIdx.x;
  const int cl = tid >> 2, seg = (tid & 3) * 16;
  const float ca = coefA[b * NC + c0 + cl], cb = coefB[b * NC + c0 + cl];
  const float4* src = (const float4*)(x + (size_t)(b * NC + c0 + cl) * NSPA + n0 + seg);
#pragma unroll
  for (int i = 0; i < 4; ++i) {
    float4 v = src[i];
    l[seg + i * 4 + 0][cl] = tob(v.x * ca + cb);
    l[seg + i * 4 + 1][cl] = tob(v.y * ca + cb);
    l[seg + i * 4 + 2][cl] = tob(v.z * ca + cb);
    l[seg + i * 4 + 3][cl] = tob(v.w * ca + cb);
  }
  __syncthreads();
#pragma unroll
  for (int i = 0; i < 2; ++i) {
    const int chunk = tid + i * 256;
    const int row = chunk >> 3, s = chunk & 7;
    *(bf16x8*)(xnT + (size_t)(b * NSPA + n0 + row) * NC + c0 + s * 8) =
        *(const bf16x8*)&l[row][s * 8];
  }
}

// ===========================================================================
// 8-phase 256x256 GEMM core (m201-template port). BK=64, 512 thr = 8 waves
// (2M x 4N), per-wave C = 128x64 = acc[8][4]. LDS 128 KB (2 dbuf x (A+B)).
// Per K-tile: 4 phases x 16 MFMA (quadrant snake (0,0)(0,1)(1,1)(1,0)),
// one half-tile (128 rows, 2 gload_lds/thread) staged per phase.
// Counted vmcnt(2) ONCE per K-tile at phase 4 (stage stream for T+1 =
// [B0@prevP4, A0@P1, B1@P2, A1@P3]; B0(T+2) issued at P4 stays in flight).
// XOR swizzle: 16B slot s of row r holds chunk s^(r&7) (r3-proven 0-conflict).
// ===========================================================================
__device__ __forceinline__ void stage_half8(const __bf16* __restrict__ src, int ld,
                                            int k0, __bf16* dst) {
  const int tid = threadIdx.x;  // 512
#pragma unroll
  for (int l = 0; l < 2; ++l) {
    const int idx = tid + l * 512;          // 0..1023 16B chunks
    const int prow = idx >> 3;              // 0..127 row within half
    const int pcs = (idx & 7) ^ (prow & 7); // inverse-swizzled source chunk
    GLDS16(src + (size_t)prow * ld + k0 + pcs * 8, dst + idx * 8);
  }
}

#define READ_AF(mh)                                                         \
  _Pragma("unroll") for (int mi = 0; mi < 4; ++mi)                          \
  _Pragma("unroll") for (int ks = 0; ks < 2; ++ks) {                        \
    const int row = wm + (mh) * 64 + mi * 16 + fr;                          \
    const int c = ks * 4 + fgh;                                             \
    af[mi][ks] = *(const bf16x8*)&sA[buf][row][(c ^ (row & 7)) * 8];        \
  }
#define READ_BF(dst, nh)                                                    \
  _Pragma("unroll") for (int ni = 0; ni < 2; ++ni)                          \
  _Pragma("unroll") for (int ks = 0; ks < 2; ++ks) {                        \
    const int row = wn + (nh) * 32 + ni * 16 + fr;                          \
    const int c = ks * 4 + fgh;                                             \
    dst[ni][ks] = *(const bf16x8*)&sB[buf][row][(c ^ (row & 7)) * 8];       \
  }
#define MFMA_Q(mh, nh, bfr)                                                 \
  __builtin_amdgcn_s_setprio(1);                                            \
  _Pragma("unroll") for (int mi = 0; mi < 4; ++mi)                          \
  _Pragma("unroll") for (int ni = 0; ni < 2; ++ni)                          \
  _Pragma("unroll") for (int ks = 0; ks < 2; ++ks)                          \
    acc[(mh) * 4 + mi][(nh) * 2 + ni] =                                     \
        __builtin_amdgcn_mfma_f32_16x16x32_bf16(                            \
            af[mi][ks], bfr[ni][ks], acc[(mh) * 4 + mi][(nh) * 2 + ni],     \
            0, 0, 0);                                                       \
  __builtin_amdgcn_s_setprio(0);

__device__ __forceinline__ void gemm8p(const __bf16* __restrict__ Ag, int lda,
                                       const __bf16* __restrict__ Bg, int ldb,
                                       int NT, __bf16 (*sA)[256][64],
                                       __bf16 (*sB)[256][64], f32x4 acc[8][4]) {
  const int tid = threadIdx.x;
  const int lane = tid & 63, wave = tid >> 6;
  const int wm = (wave >> 2) * 128;
  const int wn = (wave & 3) * 64;
  const int fr = lane & 15, fgh = lane >> 4;

  // Prologue: all 4 halves of tile 0 + B0 of tile 1 (stays in flight).
  stage_half8(Bg, ldb, 0, &sB[0][0][0]);
  stage_half8(Ag, lda, 0, &sA[0][0][0]);
  stage_half8(Bg + (size_t)128 * ldb, ldb, 0, &sB[0][128][0]);
  stage_half8(Ag + (size_t)128 * lda, lda, 0, &sA[0][128][0]);
  if (NT > 1) stage_half8(Bg, ldb, 64, &sB[1][0][0]);
  asm volatile("s_waitcnt vmcnt(2)" ::: "memory");
  __builtin_amdgcn_s_barrier();

  bf16x8 af[4][2], b0[2][2], b1[2][2];

  for (int T = 0; T < NT; ++T) {
    const int buf = T & 1;
    const int kn = (T + 1) * 64;
    // ---- phase 1: Q(0,0); stage A0(T+1)
    READ_AF(0);
    READ_BF(b0, 0);
    if (T + 1 < NT) stage_half8(Ag, lda, kn, &sA[buf ^ 1][0][0]);
    __builtin_amdgcn_s_barrier();
    MFMA_Q(0, 0, b0);
    __builtin_amdgcn_s_barrier();
    // ---- phase 2: Q(0,1); stage B1(T+1)
    READ_BF(b1, 1);
    if (T + 1 < NT) stage_half8(Bg + (size_t)128 * ldb, ldb, kn, &sB[buf ^ 1][128][0]);
    __builtin_amdgcn_s_barrier();
    MFMA_Q(0, 1, b1);
    __builtin_amdgcn_s_barrier();
    // ---- phase 3: Q(1,1); stage A1(T+1)
    READ_AF(1);
    if (T + 1 < NT) stage_half8(Ag + (size_t)128 * lda, lda, kn, &sA[buf ^ 1][128][0]);
    __builtin_amdgcn_s_barrier();
    MFMA_Q(1, 1, b1);
    __builtin_amdgcn_s_barrier();
    // ---- phase 4: Q(1,0) (b0 + af resident, no ds_reads); stage B0(T+2);
    //      counted vmcnt(2): certifies ALL of tile T+1, leaves B0(T+2) flying.
    if (T + 2 < NT) stage_half8(Bg, ldb, kn + 64, &sB[buf][0][0]);
    asm volatile("s_waitcnt vmcnt(2)" ::: "memory");
    __builtin_amdgcn_s_barrier();
    MFMA_Q(1, 0, b0);
    __builtin_amdgcn_s_barrier();
  }
}

// ---------------------------------------------------------------------------
// K3: QKV GEMM (8-phase 256^2). C[o][n] = Wqkv[o][c] x xnT[n][c]^T (+bias).
//   o <  1024 (q,k): transposed store -> qk[b][n][o]
//   o >= 1024 (v)  : natural store    -> v[b][o-1024][n]
// grid (4, 6, NB) x 512 thr
// ---------------------------------------------------------------------------
__global__ __launch_bounds__(512, 2) void qkv_gemm_kernel(
    const __bf16* __restrict__ wqb, const __bf16* __restrict__ xnT,
    const float* __restrict__ bqkv, __bf16* __restrict__ qk, __bf16* __restrict__ v) {
  const int n0 = blockIdx.x * 256, m0 = blockIdx.y * 256, b = blockIdx.z;
  __shared__ __align__(16) __bf16 sA[2][256][64];  // 64 KB
  __shared__ __align__(16) __bf16 sB[2][256][64];  // 64 KB
  f32x4 acc[8][4] = {};
  gemm8p(wqb + (size_t)m0 * NC, NC, xnT + ((size_t)b * NSPA + n0) * NC, NC,
         NC / 64, sA, sB, acc);

  const int lane = threadIdx.x & 63, wave = threadIdx.x >> 6;
  const int wmB = (wave >> 2) * 128, wn = (wave & 3) * 64;
  const int fr = lane & 15, fq4 = (lane >> 4) * 4;
  if (m0 < NSPA) {
#pragma unroll
    for (int mi = 0; mi < 8; ++mi) {
      const int m = m0 + wmB + mi * 16 + fq4;
      const float4 bias = *(const float4*)(bqkv + m);
#pragma unroll
      for (int ni = 0; ni < 4; ++ni) {
        const int n = n0 + wn + ni * 16 + fr;
        bf16x4 w;
        w[0] = tob(acc[mi][ni][0] + bias.x);
        w[1] = tob(acc[mi][ni][1] + bias.y);
        w[2] = tob(acc[mi][ni][2] + bias.z);
        w[3] = tob(acc[mi][ni][3] + bias.w);
        *(bf16x4*)(qk + ((size_t)b * NSPA + n) * NSPA + m) = w;
      }
    }
  } else {
#pragma unroll
    for (int mi = 0; mi < 8; ++mi) {
      const int m = m0 + wmB + mi * 16 + fq4;
      const float4 bias = *(const float4*)(bqkv + m);
      const int vr = m - NSPA;
#pragma unroll
      for (int ni = 0; ni < 4; ++ni) {
        const int n = n0 + wn + ni * 16 + fr;
        v[((size_t)b * NC + vr + 0) * NSPA + n] = tob(acc[mi][ni][0] + bias.x);
        v[((size_t)b * NC + vr + 1) * NSPA + n] = tob(acc[mi][ni][1] + bias.y);
        v[((size_t)b * NC + vr + 2) * NSPA + n] = tob(acc[mi][ni][2] + bias.z);
        v[((size_t)b * NC + vr + 3) * NSPA + n] = tob(acc[mi][ni][3] + bias.w);
      }
    }
  }
}

// ---------------------------------------------------------------------------
// K4: scores (swapped, 8-phase 256^2). C[j][i] = k[j][d].q[i][d];
// store P[b][i][j]*SCL.  grid (4, 4, NB) x 512 thr
// ---------------------------------------------------------------------------
__global__ __launch_bounds__(512, 2) void scores_kernel(const __bf16* __restrict__ qk,
                                                        __bf16* __restrict__ P) {
  const int i0 = blockIdx.x * 256, j0 = blockIdx.y * 256, b = blockIdx.z;
  const __bf16* base = qk + (size_t)b * NSPA * NSPA;
  __shared__ __align__(16) __bf16 sA[2][256][64];
  __shared__ __align__(16) __bf16 sB[2][256][64];
  f32x4 acc[8][4] = {};
  gemm8p(base + (size_t)j0 * NSPA + NC, NSPA, base + (size_t)i0 * NSPA, NSPA,
         NC / 64, sA, sB, acc);

  const int lane = threadIdx.x & 63, wave = threadIdx.x >> 6;
  const int wmB = (wave >> 2) * 128, wn = (wave & 3) * 64;
  const int fr = lane & 15, fq4 = (lane >> 4) * 4;
#pragma unroll
  for (int mi = 0; mi < 8; ++mi) {
    const int j = j0 + wmB + mi * 16 + fq4;
#pragma unroll
    for (int ni = 0; ni < 4; ++ni) {
      const int i = i0 + wn + ni * 16 + fr;
      bf16x4 w;
      w[0] = tob(acc[mi][ni][0] * SCL);
      w[1] = tob(acc[mi][ni][1] * SCL);
      w[2] = tob(acc[mi][ni][2] * SCL);
      w[3] = tob(acc[mi][ni][3] * SCL);
      *(bf16x4*)(P + ((size_t)b * NSPA + i) * NSPA + j) = w;
    }
  }
}

// ---------------------------------------------------------------------------
// K5: in-place row softmax, one WAVE per row (4 rows/block, shuffle-only).
// ---------------------------------------------------------------------------
__global__ void softmax_kernel(__bf16* __restrict__ P) {
  const int row = blockIdx.x * 4 + (threadIdx.x >> 6);
  const int lane = threadIdx.x & 63;
  __bf16* p = P + (size_t)row * NSPA + lane * 16;
  bf16x8 v0 = *(const bf16x8*)p;
  bf16x8 v1 = *(const bf16x8*)(p + 8);
  float f[16];
#pragma unroll
  for (int i = 0; i < 8; ++i) { f[i] = (float)v0[i]; f[8 + i] = (float)v1[i]; }
  float m = f[0];
#pragma unroll
  for (int i = 1; i < 16; ++i) m = fmaxf(m, f[i]);
#pragma unroll
  for (int off = 32; off; off >>= 1) m = fmaxf(m, __shfl_xor(m, off));
  float s = 0.f;
#pragma unroll
  for (int i = 0; i < 16; ++i) { f[i] = __expf(f[i] - m); s += f[i]; }
#pragma unroll
  for (int off = 32; off; off >>= 1) s += __shfl_xor(s, off);
  const float inv = 1.f / s;
#pragma unroll
  for (int i = 0; i < 8; ++i) { v0[i] = tob(f[i] * inv); v1[i] = tob(f[8 + i] * inv); }
  *(bf16x8*)p = v0;
  *(bf16x8*)(p + 8) = v1;
}

// ===========================================================================
// r3 2-phase 128^2 core (proven) for pv / out.
// ===========================================================================
__device__ __forceinline__ void stage_pair(const __bf16* __restrict__ A, int lda,
                                           const __bf16* __restrict__ B, int ldb,
                                           int k0, __bf16* lAf, __bf16* lBf) {
  const int tid = threadIdx.x;
#pragma unroll
  for (int i = 0; i < 4; ++i) {
    const int idx = tid + i * 256;
    const int srow = idx >> 3;
    const int ss = ((idx & 7) ^ (srow & 7)) * 8;
    GLDS16(A + (size_t)srow * lda + k0 + ss, lAf + idx * 8);
    GLDS16(B + (size_t)srow * ldb + k0 + ss, lBf + idx * 8);
  }
}

__device__ __forceinline__ void gemm_core_db(const __bf16* __restrict__ A, int lda,
                                             const __bf16* __restrict__ B, int ldb,
                                             int K, __bf16 (*lA)[128][64],
                                             __bf16 (*lB)[128][64], f32x4 acc[4][4]) {
  const int tid = threadIdx.x;
  const int lane = tid & 63, wave = tid >> 6;
  const int wm = (wave >> 1) * 64, wn = (wave & 1) * 64;
  const int fr = lane & 15, fg = (lane >> 4) * 8;
  const int nt = K >> 6;

  stage_pair(A, lda, B, ldb, 0, &lA[0][0][0], &lB[0][0][0]);
  asm volatile("s_waitcnt vmcnt(0)" ::: "memory");
  __syncthreads();
  int cur = 0;
  for (int t = 0; t < nt; ++t) {
    if (t + 1 < nt)
      stage_pair(A, lda, B, ldb, (t + 1) * 64, &lA[cur ^ 1][0][0], &lB[cur ^ 1][0][0]);
    __builtin_amdgcn_s_setprio(1);
#pragma unroll
    for (int ks = 0; ks < 2; ++ks) {
      bf16x8 af[4], bfr[4];
#pragma unroll
      for (int mi = 0; mi < 4; ++mi) {
        const int r = wm + mi * 16 + fr;
        af[mi] = *(const bf16x8*)&lA[cur][r][(ks * 32 + fg) ^ ((r & 7) << 3)];
      }
#pragma unroll
      for (int ni = 0; ni < 4; ++ni) {
        const int r = wn + ni * 16 + fr;
        bfr[ni] = *(const bf16x8*)&lB[cur][r][(ks * 32 + fg) ^ ((r & 7) << 3)];
      }
#pragma unroll
      for (int mi = 0; mi < 4; ++mi)
#pragma unroll
        for (int ni = 0; ni < 4; ++ni)
          acc[mi][ni] = __builtin_amdgcn_mfma_f32_16x16x32_bf16(af[mi], bfr[ni], acc[mi][ni], 0, 0, 0);
    }
    __builtin_amdgcn_s_setprio(0);
    if (t + 1 < nt) {
      asm volatile("s_waitcnt vmcnt(0)" ::: "memory");
      __syncthreads();
      cur ^= 1;
    }
  }
}

// ---------------------------------------------------------------------------
// K6: PV. C[d][i] = v[d][j] . P[i][j]; transposed store -> attn[b][i][d].
// ---------------------------------------------------------------------------
__global__ __launch_bounds__(256, 2) void pv_kernel(const __bf16* __restrict__ v,
                                                    const __bf16* __restrict__ P,
                                                    __bf16* __restrict__ attn) {
  const int i0 = blockIdx.x * 128, d0 = blockIdx.y * 128, b = blockIdx.z;
  __shared__ __bf16 lA[2][128][64], lB[2][128][64];
  f32x4 acc[4][4] = {};
  gemm_core_db(v + ((size_t)b * NC + d0) * NSPA, NSPA,
               P + ((size_t)b * NSPA + i0) * NSPA, NSPA, NSPA, lA, lB, acc);

  const int lane = threadIdx.x & 63, wave = threadIdx.x >> 6;
  const int wm = (wave >> 1) * 64, wn = (wave & 1) * 64;
  const int fr = lane & 15, fq4 = (lane >> 4) * 4;
#pragma unroll
  for (int mi = 0; mi < 4; ++mi) {
    const int d = d0 + wm + mi * 16 + fq4;
#pragma unroll
    for (int ni = 0; ni < 4; ++ni) {
      const int i = i0 + wn + ni * 16 + fr;
      bf16x4 w;
      w[0] = tob(acc[mi][ni][0]);
      w[1] = tob(acc[mi][ni][1]);
      w[2] = tob(acc[mi][ni][2]);
      w[3] = tob(acc[mi][ni][3]);
      *(bf16x4*)(attn + ((size_t)b * NSPA + i) * NC + d) = w;
    }
  }
}

// ---------------------------------------------------------------------------
// K7: out-proj. C[o][n] = Wout[o][c] . attn[n][c] + bias + x, fp32 natural.
// ---------------------------------------------------------------------------
__global__ __launch_bounds__(256, 2) void out_gemm_kernel(
    const __bf16* __restrict__ wob, const __bf16* __restrict__ attn,
    const float* __restrict__ bout, const float* __restrict__ x,
    float* __restrict__ out) {
  const int n0 = blockIdx.x * 128, m0 = blockIdx.y * 128, b = blockIdx.z;
  __shared__ __bf16 lA[2][128][64], lB[2][128][64];
  f32x4 acc[4][4] = {};
  gemm_core_db(wob + (size_t)m0 * NC, NC, attn + ((size_t)b * NSPA + n0) * NC, NC,
               NC, lA, lB, acc);

  const int lane = threadIdx.x & 63, wave = threadIdx.x >> 6;
  const int wm = (wave >> 1) * 64, wn = (wave & 1) * 64;
  const int fr = lane & 15, fq4 = (lane >> 4) * 4;
#pragma unroll
  for (int mi = 0; mi < 4; ++mi) {
    const int m = m0 + wm + mi * 16 + fq4;
    const float4 bias = *(const float4*)(bout + m);
#pragma unroll
    for (int ni = 0; ni < 4; ++ni) {
      const int n = n0 + wn + ni * 16 + fr;
      const size_t i0x = ((size_t)b * NC + m) * NSPA + n;
      out[i0x + 0 * NSPA] = acc[mi][ni][0] + bias.x + x[i0x + 0 * NSPA];
      out[i0x + 1 * NSPA] = acc[mi][ni][1] + bias.y + x[i0x + 1 * NSPA];
      out[i0x + 2 * NSPA] = acc[mi][ni][2] + bias.z + x[i0x + 2 * NSPA];
      out[i0x + 3 * NSPA] = acc[mi][ni][3] + bias.w + x[i0x + 3 * NSPA];
    }
  }
}

// ---------------------------------------------------------------------------
// Workspace (~66 MB):
//   coefA/coefB: 2x32 KB | xnT/attn: 16 MB | wqb 1.5 MB | wob 0.5 MB
//   v: 16 MB | P: 32 MB.  qk (32 MB) lives in d_out (dead until out_gemm).
// ---------------------------------------------------------------------------
extern "C" void kernel_launch(void* const* d_in, const int* in_sizes, int n_in,
                              void* d_out, int out_size, void* d_ws, size_t ws_size,
                              hipStream_t stream) {
  const float* x        = (const float*)d_in[0];
  const float* gn_scale = (const float*)d_in[3];
  const float* gn_bias  = (const float*)d_in[4];
  const float* w_qkv    = (const float*)d_in[5];
  const float* b_qkv    = (const float*)d_in[6];
  const float* w_out    = (const float*)d_in[7];
  const float* b_out    = (const float*)d_in[8];
  float* out = (float*)d_out;

  char* ws = (char*)d_ws;
  float*  coefA = (float*)ws;                                   // 32 KB
  float*  coefB = coefA + NB * NC;                              // 32 KB
  __bf16* xnT   = (__bf16*)(ws + (64 << 10));                   // 16 MB (also attn)
  __bf16* attn  = xnT;
  __bf16* wqb   = xnT + (size_t)NB * NSPA * NC;                 // 1.5 MB
  __bf16* wob   = wqb + (size_t)NO3 * NC;                       // 0.5 MB
  __bf16* vbuf  = wob + (size_t)NC * NC;                        // 16 MB
  __bf16* P     = vbuf + (size_t)NB * NC * NSPA;                // 32 MB
  __bf16* qk    = (__bf16*)d_out;                               // 32 MB scratch in out

  gn_stats_kernel<<<dim3(NB * 32), 256, 0, stream>>>(x, gn_scale, gn_bias, coefA, coefB);
  pack_w_kernel<<<dim3((NO3 * NC + NC * NC) / 4 / 256), 256, 0, stream>>>(w_qkv, w_out, wqb, wob);
  pack_x_kernel<<<dim3(NSPA / 64, NC / 64, NB), 256, 0, stream>>>(x, coefA, coefB, xnT);
  qkv_gemm_kernel<<<dim3(4, 6, NB), 512, 0, stream>>>(wqb, xnT, b_qkv, qk, vbuf);
  scores_kernel<<<dim3(4, 4, NB), 512, 0, stream>>>(qk, P);
  softmax_kernel<<<dim3(NB * NSPA / 4), 256, 0, stream>>>(P);
  pv_kernel<<<dim3(8, 4, NB), 256, 0, stream>>>(vbuf, P, attn);
  out_gemm_kernel<<<dim3(8, 4, NB), 256, 0, stream>>>(wob, attn, b_out, x, out);
}